// Round 1
// baseline (800.667 us; speedup 1.0000x reference)
//
#include <hip/hip_runtime.h>
#include <hip/hip_bf16.h>
#include <cstdint>
#include <cstddef>

// Problem constants
#define S_LEN   2048
#define HIDDEN  4096
#define NH      32
#define NKV     8
#define HD      128
#define NQKV    6144          // (32 + 2*8) * 128
#define WINDOW  1024
#define QSCALE  0.0883883476483184f   // 128^-0.5
#define NEGBIG  -1e30f

typedef __attribute__((ext_vector_type(8))) short  short8;   // 8 bf16 in 4 VGPRs
typedef __attribute__((ext_vector_type(4))) float  f32x4;
typedef __attribute__((ext_vector_type(4))) unsigned short us4;

__device__ __forceinline__ unsigned short f2bf(float f) {
  union { float f; uint32_t u; } v; v.f = f;
  uint32_t r = v.u + 0x7FFFu + ((v.u >> 16) & 1u);   // RNE
  return (unsigned short)(r >> 16);
}

// async global->LDS, 16B per lane. LDS dest must be wave-uniform base + lane*16.
__device__ __forceinline__ void gload_lds16(const void* g, void* l) {
  __builtin_amdgcn_global_load_lds(
      (const __attribute__((address_space(1))) unsigned int*)g,
      (__attribute__((address_space(3))) unsigned int*)l, 16, 0, 0);
}

// ---------------------------------------------------------------- cast f32->bf16
__global__ __launch_bounds__(256) void cast_f32_bf16_kernel(
    const float* __restrict__ src, unsigned short* __restrict__ dst, int n4) {
  int i = blockIdx.x * 256 + threadIdx.x;
  if (i >= n4) return;
  float4 v = ((const float4*)src)[i];
  us4 o; o.x = f2bf(v.x); o.y = f2bf(v.y); o.z = f2bf(v.z); o.w = f2bf(v.w);
  ((us4*)dst)[i] = o;
}

// --------------------------------------------- LDS-tiled transpose + cast f32->bf16
// src logical [R][C] (row stride srstride), dst [C][R] (row stride dstride).
// grid = (C/32, R/32, Z); block = (32, 8)
__global__ __launch_bounds__(256) void transpose_cast_kernel(
    const float* __restrict__ src, unsigned short* __restrict__ dst,
    long srstride, long dstride, long szoff, long dzoff) {
  __shared__ float tile[32][33];
  src += (long)blockIdx.z * szoff;
  dst += (long)blockIdx.z * dzoff;
  const int c0 = blockIdx.x * 32, r0 = blockIdx.y * 32;
  const int tx = threadIdx.x, ty = threadIdx.y;
#pragma unroll
  for (int i = 0; i < 32; i += 8)
    tile[ty + i][tx] = src[(long)(r0 + ty + i) * srstride + c0 + tx];
  __syncthreads();
#pragma unroll
  for (int i = 0; i < 32; i += 8)
    dst[(long)(c0 + ty + i) * dstride + r0 + tx] = f2bf(tile[tx][ty + i]);
}

// ---------------------------------------------------------------- RoPE cos/sin table
// T[s][f][2] for f in [0,64): angle = s * 10000^(-2f/128)
__global__ __launch_bounds__(256) void rope_table_kernel(float* __restrict__ T) {
  int idx = blockIdx.x * 256 + threadIdx.x;   // [0, S*64)
  int pos = idx >> 6, f = idx & 63;
  float inv = powf(10000.0f, -(float)(2 * f) / 128.0f);
  float ang = (float)pos * inv;
  T[idx * 2 + 0] = cosf(ang);
  T[idx * 2 + 1] = sinf(ang);
}

// ------------------------------------------------- RoPE apply + scatter to Q/K layouts
// qkv f32 [S][6144]; Qb [NH][S][HD] (scaled); Kb [NKV][S][HD]
__global__ __launch_bounds__(256) void rope_scatter_kernel(
    const float* __restrict__ qkv, const float* __restrict__ T,
    unsigned short* __restrict__ Qb, unsigned short* __restrict__ Kb) {
  const int s = blockIdx.x;
  const float* row = qkv + (long)s * NQKV;
  const float* tr  = T + (long)s * 128;
#pragma unroll
  for (int it = 0; it < 10; ++it) {
    int hp = it * 256 + threadIdx.x;     // 40 heads * 64 pair-idx = 2560
    int head = hp >> 6, dd = hp & 63;
    float c = tr[dd * 2], sn = tr[dd * 2 + 1];
    int srcoff = (head < NH) ? head * HD : HIDDEN + (head - NH) * HD;
    float x1 = row[srcoff + dd], x2 = row[srcoff + dd + 64];
    float o1 = x1 * c - x2 * sn;
    float o2 = x2 * c + x1 * sn;
    if (head < NH) {
      unsigned short* q = Qb + ((long)head * S_LEN + s) * HD;
      q[dd]      = f2bf(o1 * QSCALE);
      q[dd + 64] = f2bf(o2 * QSCALE);
    } else {
      unsigned short* k = Kb + ((long)(head - NH) * S_LEN + s) * HD;
      k[dd]      = f2bf(o1);
      k[dd + 64] = f2bf(o2);
    }
  }
}

// ---------------------------------------------------------------- GEMM  C = A * B^T
// A [M][K] bf16, BT [N][K] bf16, C [M][N] f32.  m97 structure:
// BM=BN=128, BK=32, 256 threads (2x2 waves of 64x64), global_load_lds width 16.
__global__ __launch_bounds__(256) void gemm_bt_kernel(
    const unsigned short* __restrict__ A, const unsigned short* __restrict__ BT,
    float* __restrict__ C, int M, int N, int K) {
  __shared__ unsigned short As[128][32];
  __shared__ unsigned short Bs[128][32];
  const int tid  = threadIdx.x;
  const int lane = tid & 63, wave = tid >> 6;
  const int wm = wave >> 1, wn = wave & 1;
  const int r16 = lane & 15, g4 = lane >> 4;
  const long bm = (long)blockIdx.y * 128, bn = (long)blockIdx.x * 128;

  f32x4 acc[4][4] = {};

  const int s0 = tid, s1 = tid + 256;      // 512 16B-slots per tile
  const int r0 = s0 >> 2, c0 = s0 & 3;
  const int r1 = s1 >> 2, c1 = s1 & 3;

  for (int k0 = 0; k0 < K; k0 += 32) {
    __syncthreads();   // previous compute done before restage
    gload_lds16(A  + (bm + r0) * K + k0 + c0 * 8, &As[0][0] + s0 * 8);
    gload_lds16(BT + (bn + r0) * K + k0 + c0 * 8, &Bs[0][0] + s0 * 8);
    gload_lds16(A  + (bm + r1) * K + k0 + c1 * 8, &As[0][0] + s1 * 8);
    gload_lds16(BT + (bn + r1) * K + k0 + c1 * 8, &Bs[0][0] + s1 * 8);
    __syncthreads();   // drains vmcnt (compiler emits waitcnt before barrier)

    short8 a[4], b[4];
#pragma unroll
    for (int m = 0; m < 4; ++m)
      a[m] = *(const short8*)&As[wm * 64 + m * 16 + r16][g4 * 8];
#pragma unroll
    for (int n = 0; n < 4; ++n)
      b[n] = *(const short8*)&Bs[wn * 64 + n * 16 + r16][g4 * 8];
#pragma unroll
    for (int m = 0; m < 4; ++m)
#pragma unroll
      for (int n = 0; n < 4; ++n)
        acc[m][n] = __builtin_amdgcn_mfma_f32_16x16x32_bf16(a[m], b[n], acc[m][n], 0, 0, 0);
  }

  float* Cp = C + (bm + wm * 64) * N + bn + wn * 64;
#pragma unroll
  for (int m = 0; m < 4; ++m)
#pragma unroll
    for (int n = 0; n < 4; ++n)
#pragma unroll
      for (int r = 0; r < 4; ++r)
        Cp[(long)(m * 16 + g4 * 4 + r) * N + n * 16 + r16] = acc[m][n][r];
}

// ---------------------------------------------------------------- banded flash attention
// Qb [NH][S][HD] (pre-scaled), Kb [NKV][S][HD], VT [NKV][HD][S], out attnB [S][NH*HD]
// block = (64-row q-tile, head); 4 waves x 16 rows. K-tile = 64.
__global__ __launch_bounds__(256) void attn_kernel(
    const unsigned short* __restrict__ Qb, const unsigned short* __restrict__ Kb,
    const unsigned short* __restrict__ VT, unsigned short* __restrict__ attnB) {
  const int h  = blockIdx.y;
  const int q0 = blockIdx.x * 64;
  const int kv = h >> 2;                      // H/KV = 4
  const int lane = threadIdx.x & 63, wave = threadIdx.x >> 6;
  const int r16 = lane & 15, g4 = lane >> 4;
  const int qrow = q0 + wave * 16;

  // wave-private P staging; rows padded to 72 (144B) to break bank conflicts
  __shared__ unsigned short Pl[4][16][72];

  // Q fragments (held across all k-tiles)
  short8 qf[4];
  const unsigned short* Qrow = Qb + ((long)h * S_LEN + qrow + r16) * HD;
#pragma unroll
  for (int kk = 0; kk < 4; ++kk)
    qf[kk] = *(const short8*)(Qrow + kk * 32 + g4 * 8);

  float m_[4] = {NEGBIG, NEGBIG, NEGBIG, NEGBIG};
  float l_[4] = {0.f, 0.f, 0.f, 0.f};
  f32x4 Of[8] = {};

  int jstart = q0 - (WINDOW - 1);
  jstart = (jstart < 0) ? 0 : (jstart & ~63);

  for (int j0 = jstart; j0 < q0 + 64; j0 += 64) {
    // ---- S = Q K^T  (64 cols of this tile)
    f32x4 sf[4] = {};
    const unsigned short* Kt = Kb + ((long)kv * S_LEN + j0) * HD;
#pragma unroll
    for (int kk = 0; kk < 4; ++kk) {
#pragma unroll
      for (int n = 0; n < 4; ++n) {
        short8 kf = *(const short8*)(Kt + (long)(n * 16 + r16) * HD + kk * 32 + g4 * 8);
        sf[n] = __builtin_amdgcn_mfma_f32_16x16x32_bf16(qf[kk], kf, sf[n], 0, 0, 0);
      }
    }
    // ---- softcap + band mask + per-row max
    float pm[4] = {NEGBIG, NEGBIG, NEGBIG, NEGBIG};
#pragma unroll
    for (int n = 0; n < 4; ++n) {
      int j = j0 + n * 16 + r16;
#pragma unroll
      for (int r = 0; r < 4; ++r) {
        int i = qrow + g4 * 4 + r;
        float v = sf[n][r];
        // 50*tanh(v/50) = 50*(1 - 2/(exp(2v/50)+1)); inf-safe at both extremes
        float e = __expf(v * 0.04f);
        v = 50.0f * (1.0f - 2.0f / (e + 1.0f));
        bool ok = (j <= i) && (j >= i - (WINDOW - 1));
        v = ok ? v : NEGBIG;
        sf[n][r] = v;
        pm[r] = fmaxf(pm[r], v);
      }
    }
#pragma unroll
    for (int r = 0; r < 4; ++r) {
#pragma unroll
      for (int off = 1; off < 16; off <<= 1)
        pm[r] = fmaxf(pm[r], __shfl_xor(pm[r], off, 64));
    }
    // ---- online softmax update
    float rs[4];
#pragma unroll
    for (int r = 0; r < 4; ++r) {
      float mn = fmaxf(m_[r], pm[r]);
      float sc = __expf(m_[r] - mn);
      m_[r] = mn;
      l_[r] *= sc;
#pragma unroll
      for (int n = 0; n < 8; ++n) Of[n][r] *= sc;
      rs[r] = 0.f;
    }
#pragma unroll
    for (int n = 0; n < 4; ++n)
#pragma unroll
      for (int r = 0; r < 4; ++r) {
        float p = __expf(sf[n][r] - m_[r]);
        rs[r] += p;
        Pl[wave][g4 * 4 + r][n * 16 + r16] = f2bf(p);
      }
#pragma unroll
    for (int r = 0; r < 4; ++r) {
#pragma unroll
      for (int off = 1; off < 16; off <<= 1)
        rs[r] += __shfl_xor(rs[r], off, 64);
      l_[r] += rs[r];
    }
    // ---- O += P V   (wave-private LDS; same-wave RAW ordered by lgkmcnt)
    const unsigned short* Vt = VT + (long)kv * HD * S_LEN + j0;
#pragma unroll
    for (int ks = 0; ks < 2; ++ks) {
      short8 af = *(const short8*)&Pl[wave][r16][ks * 32 + g4 * 8];
#pragma unroll
      for (int n = 0; n < 8; ++n) {
        short8 vf = *(const short8*)(Vt + (long)(n * 16 + r16) * S_LEN + ks * 32 + g4 * 8);
        Of[n] = __builtin_amdgcn_mfma_f32_16x16x32_bf16(af, vf, Of[n], 0, 0, 0);
      }
    }
  }
  // ---- epilogue: normalize, write [S][NH*HD] bf16
#pragma unroll
  for (int n = 0; n < 8; ++n)
#pragma unroll
    for (int r = 0; r < 4; ++r) {
      int i = qrow + g4 * 4 + r;
      float o = Of[n][r] / l_[r];
      attnB[(long)i * (NH * HD) + h * HD + n * 16 + r16] = f2bf(o);
    }
}

// ---------------------------------------------------------------- launcher
extern "C" void kernel_launch(void* const* d_in, const int* in_sizes, int n_in,
                              void* d_out, int out_size, void* d_ws, size_t ws_size,
                              hipStream_t stream) {
  const float* hidden = (const float*)d_in[0];
  const float* qkv_w  = (const float*)d_in[5];
  const float* o_w    = (const float*)d_in[6];
  float* out = (float*)d_out;
  char* ws = (char*)d_ws;

  // workspace layout (bytes)
  unsigned short* hidB  = (unsigned short*)(ws);                    //  16 MB: [S][HID] bf16
  unsigned short* wqkvT = (unsigned short*)(ws + 16777216L);        //  48 MB: [NQKV][HID] bf16
  unsigned short* woT   = (unsigned short*)(ws + 67108864L);        //  32 MB: [HID][NH*HD] bf16
  float*          qkvF  = (float*)        (ws + 100663296L);        //  48 MB: [S][NQKV] f32
  unsigned short* Qb    = (unsigned short*)(ws + 150994944L);       //  16 MB: [NH][S][HD]
  unsigned short* Kb    = (unsigned short*)(ws + 167772160L);       //   4 MB: [NKV][S][HD]
  unsigned short* VT    = (unsigned short*)(ws + 171966464L);       //   4 MB: [NKV][HD][S]
  unsigned short* attnB = (unsigned short*)(ws + 176160768L);       //  16 MB: [S][NH*HD]
  float*          ropeT = (float*)        (ws + 192937984L);        //   1 MB: [S][64][2]

  // 1) hidden f32 -> bf16
  cast_f32_bf16_kernel<<<(S_LEN * HIDDEN / 4 + 255) / 256, 256, 0, stream>>>(
      hidden, hidB, S_LEN * HIDDEN / 4);
  // 2) qkv_w [HID][NQKV] -> wqkvT [NQKV][HID]
  transpose_cast_kernel<<<dim3(NQKV / 32, HIDDEN / 32, 1), dim3(32, 8), 0, stream>>>(
      qkv_w, wqkvT, NQKV, HIDDEN, 0, 0);
  // 3) o_w [NH*HD][HID] -> woT [HID][NH*HD]
  transpose_cast_kernel<<<dim3(HIDDEN / 32, NH * HD / 32, 1), dim3(32, 8), 0, stream>>>(
      o_w, woT, HIDDEN, NH * HD, 0, 0);
  // 4) rope table
  rope_table_kernel<<<(S_LEN * 64) / 256, 256, 0, stream>>>(ropeT);
  // 5) qkv = hidden @ qkv_w   (f32 out)
  gemm_bt_kernel<<<dim3(NQKV / 128, S_LEN / 128), 256, 0, stream>>>(
      hidB, wqkvT, qkvF, S_LEN, NQKV, HIDDEN);
  // 6) RoPE + scatter Q/K
  rope_scatter_kernel<<<S_LEN, 256, 0, stream>>>(qkvF, ropeT, Qb, Kb);
  // 7) V slice of qkv -> VT [NKV][HD][S]   (per-head transpose)
  transpose_cast_kernel<<<dim3(HD / 32, S_LEN / 32, NKV), dim3(32, 8), 0, stream>>>(
      qkvF + HIDDEN + NKV * HD, VT, NQKV, S_LEN, HD, (long)HD * S_LEN);
  // 8) attention
  attn_kernel<<<dim3(S_LEN / 64, NH), 256, 0, stream>>>(Qb, Kb, VT, attnB);
  // 9) out = attn @ o_w   (f32 out to d_out)
  gemm_bt_kernel<<<dim3(NH * HD / 128, S_LEN / 128), 256, 0, stream>>>(
      attnB, woT, out, S_LEN, NH * HD, HIDDEN);
}

// Round 5
// 749.929 us; speedup vs baseline: 1.0677x; 1.0677x over previous
//
#include <hip/hip_runtime.h>
#include <hip/hip_bf16.h>
#include <cstdint>
#include <cstddef>

// Problem constants
#define S_LEN   2048
#define HIDDEN  4096
#define NH      32
#define NKV     8
#define HD      128
#define NQKV    6144          // (32 + 2*8) * 128
#define WINDOW  1024
#define QSCALE  0.0883883476483184f   // 128^-0.5
#define NEGBIG  -1e30f

typedef __attribute__((ext_vector_type(8))) short  short8;   // 8 bf16 in 4 VGPRs
typedef __attribute__((ext_vector_type(4))) float  f32x4;
typedef __attribute__((ext_vector_type(4))) unsigned short us4;

__device__ __forceinline__ unsigned short f2bf(float f) {
  union { float f; uint32_t u; } v; v.f = f;
  uint32_t r = v.u + 0x7FFFu + ((v.u >> 16) & 1u);   // RNE
  return (unsigned short)(r >> 16);
}

// async global->LDS, 16B per lane. LDS dest must be wave-uniform base + lane*16.
__device__ __forceinline__ void gload_lds16(const void* g, void* l) {
  __builtin_amdgcn_global_load_lds(
      (const __attribute__((address_space(1))) unsigned int*)g,
      (__attribute__((address_space(3))) unsigned int*)l, 16, 0, 0);
}

// ---------------------------------------------------------------- cast f32->bf16
__global__ __launch_bounds__(256) void cast_f32_bf16_kernel(
    const float* __restrict__ src, unsigned short* __restrict__ dst, int n4) {
  int i = blockIdx.x * 256 + threadIdx.x;
  if (i >= n4) return;
  float4 v = ((const float4*)src)[i];
  us4 o; o.x = f2bf(v.x); o.y = f2bf(v.y); o.z = f2bf(v.z); o.w = f2bf(v.w);
  ((us4*)dst)[i] = o;
}

// --------------------------------------------- LDS-tiled transpose + cast f32->bf16
// src logical [R][C] (row stride srstride), dst [C][R] (row stride dstride).
// grid = (C/32, R/32, Z); block = (32, 8)
__global__ __launch_bounds__(256) void transpose_cast_kernel(
    const float* __restrict__ src, unsigned short* __restrict__ dst,
    long srstride, long dstride, long szoff, long dzoff) {
  __shared__ float tile[32][33];
  src += (long)blockIdx.z * szoff;
  dst += (long)blockIdx.z * dzoff;
  const int c0 = blockIdx.x * 32, r0 = blockIdx.y * 32;
  const int tx = threadIdx.x, ty = threadIdx.y;
#pragma unroll
  for (int i = 0; i < 32; i += 8)
    tile[ty + i][tx] = src[(long)(r0 + ty + i) * srstride + c0 + tx];
  __syncthreads();
#pragma unroll
  for (int i = 0; i < 32; i += 8)
    dst[(long)(c0 + ty + i) * dstride + r0 + tx] = f2bf(tile[tx][ty + i]);
}

// ---------------------------------------------------------------- RoPE cos/sin table
// T[s][f][2] for f in [0,64): angle = s * 10000^(-2f/128)
__global__ __launch_bounds__(256) void rope_table_kernel(float* __restrict__ T) {
  int idx = blockIdx.x * 256 + threadIdx.x;   // [0, S*64)
  int pos = idx >> 6, f = idx & 63;
  float inv = powf(10000.0f, -(float)(2 * f) / 128.0f);
  float ang = (float)pos * inv;
  T[idx * 2 + 0] = cosf(ang);
  T[idx * 2 + 1] = sinf(ang);
}

// ------------------------------------------------- RoPE apply + scatter to Q/K layouts
// qkv f32 [S][6144]; Qb [NH][S][HD] (scaled); Kb [NKV][S][HD]
__global__ __launch_bounds__(256) void rope_scatter_kernel(
    const float* __restrict__ qkv, const float* __restrict__ T,
    unsigned short* __restrict__ Qb, unsigned short* __restrict__ Kb) {
  const int s = blockIdx.x;
  const float* row = qkv + (long)s * NQKV;
  const float* tr  = T + (long)s * 128;
#pragma unroll
  for (int it = 0; it < 10; ++it) {
    int hp = it * 256 + threadIdx.x;     // 40 heads * 64 pair-idx = 2560
    int head = hp >> 6, dd = hp & 63;
    float c = tr[dd * 2], sn = tr[dd * 2 + 1];
    int srcoff = (head < NH) ? head * HD : HIDDEN + (head - NH) * HD;
    float x1 = row[srcoff + dd], x2 = row[srcoff + dd + 64];
    float o1 = x1 * c - x2 * sn;
    float o2 = x2 * c + x1 * sn;
    if (head < NH) {
      unsigned short* q = Qb + ((long)head * S_LEN + s) * HD;
      q[dd]      = f2bf(o1 * QSCALE);
      q[dd + 64] = f2bf(o2 * QSCALE);
    } else {
      unsigned short* k = Kb + ((long)(head - NH) * S_LEN + s) * HD;
      k[dd]      = f2bf(o1);
      k[dd + 64] = f2bf(o2);
    }
  }
}

// ---------------------------------------------------------------- GEMM  C = A * B^T
// A [M][K] bf16, BT [N][K] bf16, C [M][N] f32.  m97 structure:
// BM=BN=128, BK=32, 256 threads (2x2 waves of 64x64), global_load_lds width 16.
// T1 XCD swizzle: grid sizes are multiples of 8 (768 / 512 wgs) so the simple
// chunked remap is bijective; each XCD's L2 then sees a contiguous tile range.
__global__ __launch_bounds__(256) void gemm_bt_kernel(
    const unsigned short* __restrict__ A, const unsigned short* __restrict__ BT,
    float* __restrict__ C, int M, int N, int K) {
  __shared__ unsigned short As[128][32];
  __shared__ unsigned short Bs[128][32];
  const int tid  = threadIdx.x;
  const int lane = tid & 63, wave = tid >> 6;
  const int wm = wave >> 1, wn = wave & 1;
  const int r16 = lane & 15, g4 = lane >> 4;

  // XCD-aware swizzle (requires nwg % 8 == 0; holds for both launches)
  const int nwg  = gridDim.x * gridDim.y;
  const int orig = blockIdx.y * gridDim.x + blockIdx.x;
  const int cpx  = nwg >> 3;
  const int swz  = (orig & 7) * cpx + (orig >> 3);
  const long bm = (long)(swz / gridDim.x) * 128;
  const long bn = (long)(swz % gridDim.x) * 128;

  f32x4 acc[4][4] = {};

  const int s0 = tid, s1 = tid + 256;      // 512 16B-slots per tile
  const int r0 = s0 >> 2, c0 = s0 & 3;
  const int r1 = s1 >> 2, c1 = s1 & 3;

  for (int k0 = 0; k0 < K; k0 += 32) {
    __syncthreads();   // previous compute done before restage
    gload_lds16(A  + (bm + r0) * K + k0 + c0 * 8, &As[0][0] + s0 * 8);
    gload_lds16(BT + (bn + r0) * K + k0 + c0 * 8, &Bs[0][0] + s0 * 8);
    gload_lds16(A  + (bm + r1) * K + k0 + c1 * 8, &As[0][0] + s1 * 8);
    gload_lds16(BT + (bn + r1) * K + k0 + c1 * 8, &Bs[0][0] + s1 * 8);
    __syncthreads();   // drains vmcnt (compiler emits waitcnt before barrier)

    short8 a[4], b[4];
#pragma unroll
    for (int m = 0; m < 4; ++m)
      a[m] = *(const short8*)&As[wm * 64 + m * 16 + r16][g4 * 8];
#pragma unroll
    for (int n = 0; n < 4; ++n)
      b[n] = *(const short8*)&Bs[wn * 64 + n * 16 + r16][g4 * 8];
#pragma unroll
    for (int m = 0; m < 4; ++m)
#pragma unroll
      for (int n = 0; n < 4; ++n)
        acc[m][n] = __builtin_amdgcn_mfma_f32_16x16x32_bf16(a[m], b[n], acc[m][n], 0, 0, 0);
  }

  float* Cp = C + (bm + wm * 64) * N + bn + wn * 64;
#pragma unroll
  for (int m = 0; m < 4; ++m)
#pragma unroll
    for (int n = 0; n < 4; ++n)
#pragma unroll
      for (int r = 0; r < 4; ++r)
        Cp[(long)(m * 16 + g4 * 4 + r) * N + n * 16 + r16] = acc[m][n][r];
}

// ---------------------------------------------------------------- banded flash attention
// Qb [NH][S][HD] (pre-scaled), Kb [NKV][S][HD], VT [NKV][HD][S], out attnB [S][NH*HD]
// block = (64-row q-tile, head); 4 waves x 16 rows. K-tile = 64.
// Softcap bounds scores to (-50,50) => exp(s) <= e^50 fits f32/bf16 with huge
// headroom, so NO running max / rescale is needed: p = exp(softcap(s)), l = sum p,
// reduced once in the epilogue. This removes all per-tile cross-lane ops.
__global__ __launch_bounds__(256) void attn_kernel(
    const unsigned short* __restrict__ Qb, const unsigned short* __restrict__ Kb,
    const unsigned short* __restrict__ VT, unsigned short* __restrict__ attnB) {
  const int h  = blockIdx.y;
  // diagonal remap: CU c would otherwise get 4 blocks of identical q-tile index
  // (grid.x=32 divides 256) -> 17x work imbalance across CUs. Spread it.
  const int qt = (blockIdx.x + blockIdx.y) & 31;
  const int q0 = qt * 64;
  const int kv = h >> 2;                      // H/KV = 4
  const int lane = threadIdx.x & 63, wave = threadIdx.x >> 6;
  const int r16 = lane & 15, g4 = lane >> 4;
  const int qrow = q0 + wave * 16;

  // wave-private P staging; rows padded to 72 (144B) to break bank conflicts
  __shared__ unsigned short Pl[4][16][72];

  // Q fragments (held across all k-tiles)
  short8 qf[4];
  const unsigned short* Qrow = Qb + ((long)h * S_LEN + qrow + r16) * HD;
#pragma unroll
  for (int kk = 0; kk < 4; ++kk)
    qf[kk] = *(const short8*)(Qrow + kk * 32 + g4 * 8);

  float l_[4] = {0.f, 0.f, 0.f, 0.f};
  f32x4 Of[8] = {};

  int jstart = q0 - (WINDOW - 1);
  jstart = (jstart < 0) ? 0 : (jstart & ~63);

  for (int j0 = jstart; j0 < q0 + 64; j0 += 64) {
    // ---- S = Q K^T  (64 cols of this tile)
    f32x4 sf[4] = {};
    const unsigned short* Kt = Kb + ((long)kv * S_LEN + j0) * HD;
#pragma unroll
    for (int kk = 0; kk < 4; ++kk) {
#pragma unroll
      for (int n = 0; n < 4; ++n) {
        short8 kf = *(const short8*)(Kt + (long)(n * 16 + r16) * HD + kk * 32 + g4 * 8);
        sf[n] = __builtin_amdgcn_mfma_f32_16x16x32_bf16(qf[kk], kf, sf[n], 0, 0, 0);
      }
    }
    // ---- softcap + band mask + p = exp(capped); accumulate l in-lane (no shfl)
#pragma unroll
    for (int n = 0; n < 4; ++n) {
      int j = j0 + n * 16 + r16;
#pragma unroll
      for (int r = 0; r < 4; ++r) {
        int i = qrow + g4 * 4 + r;
        float v = sf[n][r];
        // 50*tanh(v/50) = 50 - 100/(exp(2v/50)+1); inf-safe at both extremes
        float e = __expf(v * 0.04f);
        float cap = 50.0f - 100.0f * __builtin_amdgcn_rcpf(e + 1.0f);
        bool ok = (j <= i) && (j >= i - (WINDOW - 1));
        float p = ok ? __expf(cap) : 0.0f;   // p in [0, e^50], f32-safe
        l_[r] += p;
        Pl[wave][g4 * 4 + r][n * 16 + r16] = f2bf(p);
      }
    }
    // ---- O += P V   (wave-private LDS; same-wave RAW ordered by lgkmcnt)
    const unsigned short* Vt = VT + (long)kv * HD * S_LEN + j0;
#pragma unroll
    for (int ks = 0; ks < 2; ++ks) {
      short8 af = *(const short8*)&Pl[wave][r16][ks * 32 + g4 * 8];
#pragma unroll
      for (int n = 0; n < 8; ++n) {
        short8 vf = *(const short8*)(Vt + (long)(n * 16 + r16) * S_LEN + ks * 32 + g4 * 8);
        Of[n] = __builtin_amdgcn_mfma_f32_16x16x32_bf16(af, vf, Of[n], 0, 0, 0);
      }
    }
  }
  // ---- epilogue: one l-reduction across the 16 k-col lanes, normalize, store
#pragma unroll
  for (int r = 0; r < 4; ++r) {
#pragma unroll
    for (int off = 1; off < 16; off <<= 1)
      l_[r] += __shfl_xor(l_[r], off, 64);
    l_[r] = __builtin_amdgcn_rcpf(l_[r]);
  }
#pragma unroll
  for (int n = 0; n < 8; ++n)
#pragma unroll
    for (int r = 0; r < 4; ++r) {
      int i = qrow + g4 * 4 + r;
      float o = Of[n][r] * l_[r];
      attnB[(long)i * (NH * HD) + h * HD + n * 16 + r16] = f2bf(o);
    }
}

// ---------------------------------------------------------------- launcher
extern "C" void kernel_launch(void* const* d_in, const int* in_sizes, int n_in,
                              void* d_out, int out_size, void* d_ws, size_t ws_size,
                              hipStream_t stream) {
  const float* hidden = (const float*)d_in[0];
  const float* qkv_w  = (const float*)d_in[5];
  const float* o_w    = (const float*)d_in[6];
  float* out = (float*)d_out;
  char* ws = (char*)d_ws;

  // workspace layout (bytes)
  unsigned short* hidB  = (unsigned short*)(ws);                    //  16 MB: [S][HID] bf16
  unsigned short* wqkvT = (unsigned short*)(ws + 16777216L);        //  48 MB: [NQKV][HID] bf16
  unsigned short* woT   = (unsigned short*)(ws + 67108864L);        //  32 MB: [HID][NH*HD] bf16
  float*          qkvF  = (float*)        (ws + 100663296L);        //  48 MB: [S][NQKV] f32
  unsigned short* Qb    = (unsigned short*)(ws + 150994944L);       //  16 MB: [NH][S][HD]
  unsigned short* Kb    = (unsigned short*)(ws + 167772160L);       //   4 MB: [NKV][S][HD]
  unsigned short* VT    = (unsigned short*)(ws + 171966464L);       //   4 MB: [NKV][HD][S]
  unsigned short* attnB = (unsigned short*)(ws + 176160768L);       //  16 MB: [S][NH*HD]
  float*          ropeT = (float*)        (ws + 192937984L);        //   1 MB: [S][64][2]

  // 1) hidden f32 -> bf16
  cast_f32_bf16_kernel<<<(S_LEN * HIDDEN / 4 + 255) / 256, 256, 0, stream>>>(
      hidden, hidB, S_LEN * HIDDEN / 4);
  // 2) qkv_w [HID][NQKV] -> wqkvT [NQKV][HID]
  transpose_cast_kernel<<<dim3(NQKV / 32, HIDDEN / 32, 1), dim3(32, 8), 0, stream>>>(
      qkv_w, wqkvT, NQKV, HIDDEN, 0, 0);
  // 3) o_w [NH*HD][HID] -> woT [HID][NH*HD]
  transpose_cast_kernel<<<dim3(HIDDEN / 32, NH * HD / 32, 1), dim3(32, 8), 0, stream>>>(
      o_w, woT, HIDDEN, NH * HD, 0, 0);
  // 4) rope table
  rope_table_kernel<<<(S_LEN * 64) / 256, 256, 0, stream>>>(ropeT);
  // 5) qkv = hidden @ qkv_w   (f32 out)
  gemm_bt_kernel<<<dim3(NQKV / 128, S_LEN / 128), 256, 0, stream>>>(
      hidB, wqkvT, qkvF, S_LEN, NQKV, HIDDEN);
  // 6) RoPE + scatter Q/K
  rope_scatter_kernel<<<S_LEN, 256, 0, stream>>>(qkvF, ropeT, Qb, Kb);
  // 7) V slice of qkv -> VT [NKV][HD][S]   (per-head transpose)
  transpose_cast_kernel<<<dim3(HD / 32, S_LEN / 32, NKV), dim3(32, 8), 0, stream>>>(
      qkvF + HIDDEN + NKV * HD, VT, NQKV, S_LEN, HD, (long)HD * S_LEN);
  // 8) attention
  attn_kernel<<<dim3(S_LEN / 64, NH), 256, 0, stream>>>(Qb, Kb, VT, attnB);
  // 9) out = attn @ o_w   (f32 out to d_out)
  gemm_bt_kernel<<<dim3(NH * HD / 128, S_LEN / 128), 256, 0, stream>>>(
      attnB, woT, out, S_LEN, NH * HD, HIDDEN);
}

// Round 6
// 619.655 us; speedup vs baseline: 1.2921x; 1.2102x over previous
//
#include <hip/hip_runtime.h>
#include <hip/hip_bf16.h>
#include <cstdint>
#include <cstddef>

// Problem constants
#define S_LEN   2048
#define HIDDEN  4096
#define NH      32
#define NKV     8
#define HD      128
#define NQKV    6144          // (32 + 2*8) * 128
#define WINDOW  1024
#define QSCALE  0.0883883476483184f   // 128^-0.5
#define NEGBIG  -1e30f

typedef __attribute__((ext_vector_type(8))) short  short8;   // 8 bf16 in 4 VGPRs
typedef __attribute__((ext_vector_type(4))) float  f32x4;
typedef __attribute__((ext_vector_type(4))) unsigned short us4;

__device__ __forceinline__ unsigned short f2bf(float f) {
  union { float f; uint32_t u; } v; v.f = f;
  uint32_t r = v.u + 0x7FFFu + ((v.u >> 16) & 1u);   // RNE
  return (unsigned short)(r >> 16);
}

// async global->LDS, 16B per lane. LDS dest must be wave-uniform base + lane*16.
__device__ __forceinline__ void gload_lds16(const void* g, void* l) {
  __builtin_amdgcn_global_load_lds(
      (const __attribute__((address_space(1))) unsigned int*)g,
      (__attribute__((address_space(3))) unsigned int*)l, 16, 0, 0);
}

// ---------------------------------------------------------------- cast f32->bf16
__global__ __launch_bounds__(256) void cast_f32_bf16_kernel(
    const float* __restrict__ src, unsigned short* __restrict__ dst, int n4) {
  int i = blockIdx.x * 256 + threadIdx.x;
  if (i >= n4) return;
  float4 v = ((const float4*)src)[i];
  us4 o; o.x = f2bf(v.x); o.y = f2bf(v.y); o.z = f2bf(v.z); o.w = f2bf(v.w);
  ((us4*)dst)[i] = o;
}

// --------------------------------------------- LDS-tiled transpose + cast f32->bf16
// src logical [R][C] (row stride srstride), dst [C][R] (row stride dstride).
// grid = (C/32, R/32, Z); block = (32, 8)
__global__ __launch_bounds__(256) void transpose_cast_kernel(
    const float* __restrict__ src, unsigned short* __restrict__ dst,
    long srstride, long dstride, long szoff, long dzoff) {
  __shared__ float tile[32][33];
  src += (long)blockIdx.z * szoff;
  dst += (long)blockIdx.z * dzoff;
  const int c0 = blockIdx.x * 32, r0 = blockIdx.y * 32;
  const int tx = threadIdx.x, ty = threadIdx.y;
#pragma unroll
  for (int i = 0; i < 32; i += 8)
    tile[ty + i][tx] = src[(long)(r0 + ty + i) * srstride + c0 + tx];
  __syncthreads();
#pragma unroll
  for (int i = 0; i < 32; i += 8)
    dst[(long)(c0 + ty + i) * dstride + r0 + tx] = f2bf(tile[tx][ty + i]);
}

// ---------------------------------------------------------------- RoPE cos/sin table
// T[s][f][2] for f in [0,64): angle = s * 10000^(-2f/128)
__global__ __launch_bounds__(256) void rope_table_kernel(float* __restrict__ T) {
  int idx = blockIdx.x * 256 + threadIdx.x;   // [0, S*64)
  int pos = idx >> 6, f = idx & 63;
  float inv = powf(10000.0f, -(float)(2 * f) / 128.0f);
  float ang = (float)pos * inv;
  T[idx * 2 + 0] = cosf(ang);
  T[idx * 2 + 1] = sinf(ang);
}

// ------------------------------------------------- RoPE apply + scatter to Q/K layouts
// qkv f32 [S][6144]; Qb [NH][S][HD] (scaled); Kb [NKV][S][HD]
__global__ __launch_bounds__(256) void rope_scatter_kernel(
    const float* __restrict__ qkv, const float* __restrict__ T,
    unsigned short* __restrict__ Qb, unsigned short* __restrict__ Kb) {
  const int s = blockIdx.x;
  const float* row = qkv + (long)s * NQKV;
  const float* tr  = T + (long)s * 128;
#pragma unroll
  for (int it = 0; it < 10; ++it) {
    int hp = it * 256 + threadIdx.x;     // 40 heads * 64 pair-idx = 2560
    int head = hp >> 6, dd = hp & 63;
    float c = tr[dd * 2], sn = tr[dd * 2 + 1];
    int srcoff = (head < NH) ? head * HD : HIDDEN + (head - NH) * HD;
    float x1 = row[srcoff + dd], x2 = row[srcoff + dd + 64];
    float o1 = x1 * c - x2 * sn;
    float o2 = x2 * c + x1 * sn;
    if (head < NH) {
      unsigned short* q = Qb + ((long)head * S_LEN + s) * HD;
      q[dd]      = f2bf(o1 * QSCALE);
      q[dd + 64] = f2bf(o2 * QSCALE);
    } else {
      unsigned short* k = Kb + ((long)(head - NH) * S_LEN + s) * HD;
      k[dd]      = f2bf(o1);
      k[dd + 64] = f2bf(o2);
    }
  }
}

// ---------------------------------------------------------------- GEMM  C = A * B^T
// A [M][K] bf16, BT [N][K] bf16, C [M][N] f32.  m97 structure:
// BM=BN=128, BK=32, 256 threads (2x2 waves of 64x64), global_load_lds width 16.
// T1 XCD swizzle: grid sizes are multiples of 8 (768 / 512 wgs) so the simple
// chunked remap is bijective; each XCD's L2 then sees a contiguous tile range.
__global__ __launch_bounds__(256) void gemm_bt_kernel(
    const unsigned short* __restrict__ A, const unsigned short* __restrict__ BT,
    float* __restrict__ C, int M, int N, int K) {
  __shared__ unsigned short As[128][32];
  __shared__ unsigned short Bs[128][32];
  const int tid  = threadIdx.x;
  const int lane = tid & 63, wave = tid >> 6;
  const int wm = wave >> 1, wn = wave & 1;
  const int r16 = lane & 15, g4 = lane >> 4;

  // XCD-aware swizzle (requires nwg % 8 == 0; holds for both launches)
  const int nwg  = gridDim.x * gridDim.y;
  const int orig = blockIdx.y * gridDim.x + blockIdx.x;
  const int cpx  = nwg >> 3;
  const int swz  = (orig & 7) * cpx + (orig >> 3);
  const long bm = (long)(swz / gridDim.x) * 128;
  const long bn = (long)(swz % gridDim.x) * 128;

  f32x4 acc[4][4] = {};

  const int s0 = tid, s1 = tid + 256;      // 512 16B-slots per tile
  const int r0 = s0 >> 2, c0 = s0 & 3;
  const int r1 = s1 >> 2, c1 = s1 & 3;

  for (int k0 = 0; k0 < K; k0 += 32) {
    __syncthreads();   // previous compute done before restage
    gload_lds16(A  + (bm + r0) * K + k0 + c0 * 8, &As[0][0] + s0 * 8);
    gload_lds16(BT + (bn + r0) * K + k0 + c0 * 8, &Bs[0][0] + s0 * 8);
    gload_lds16(A  + (bm + r1) * K + k0 + c1 * 8, &As[0][0] + s1 * 8);
    gload_lds16(BT + (bn + r1) * K + k0 + c1 * 8, &Bs[0][0] + s1 * 8);
    __syncthreads();   // drains vmcnt (compiler emits waitcnt before barrier)

    short8 a[4], b[4];
#pragma unroll
    for (int m = 0; m < 4; ++m)
      a[m] = *(const short8*)&As[wm * 64 + m * 16 + r16][g4 * 8];
#pragma unroll
    for (int n = 0; n < 4; ++n)
      b[n] = *(const short8*)&Bs[wn * 64 + n * 16 + r16][g4 * 8];
#pragma unroll
    for (int m = 0; m < 4; ++m)
#pragma unroll
      for (int n = 0; n < 4; ++n)
        acc[m][n] = __builtin_amdgcn_mfma_f32_16x16x32_bf16(a[m], b[n], acc[m][n], 0, 0, 0);
  }

  float* Cp = C + (bm + wm * 64) * N + bn + wn * 64;
#pragma unroll
  for (int m = 0; m < 4; ++m)
#pragma unroll
    for (int n = 0; n < 4; ++n)
#pragma unroll
      for (int r = 0; r < 4; ++r)
        Cp[(long)(m * 16 + g4 * 4 + r) * N + n * 16 + r16] = acc[m][n][r];
}

// ---------------------------------------------------------------- banded flash attention
// Qb [NH][S][HD] (pre-scaled), Kb [NKV][S][HD], VT [NKV][HD][S], out attnB [S][NH*HD]
// block = (64-row q-tile, head); 4 waves x 16 rows. K-tile = 64.
//
// R5 change: K and V tiles are cooperatively staged in LDS once per block
// (was: each of 4 waves loading the same fragments from global -> 4x vector-mem
// traffic, latency-bound at 227us with all pipes <15%).
// LDS layouts are XOR-swizzled (chunk ^= row&7, 16B chunks) to make the
// row-strided ds_read_b128 fragment reads bank-conflict-free; since
// global_load_lds writes lane-linearly, the swizzle is applied by permuting the
// GLOBAL source chunk per rule "both-sides-or-neither" (involution on both ends).
__global__ __launch_bounds__(256) void attn_kernel(
    const unsigned short* __restrict__ Qb, const unsigned short* __restrict__ Kb,
    const unsigned short* __restrict__ VT, unsigned short* __restrict__ attnB) {
  const int h  = blockIdx.y;
  // diagonal remap: CU c would otherwise get 4 blocks of identical q-tile index
  // (grid.x=32 divides 256) -> 17x work imbalance across CUs. Spread it.
  const int qt = (blockIdx.x + blockIdx.y) & 31;
  const int q0 = qt * 64;
  const int kv = h >> 2;                      // H/KV = 4
  const int tid  = threadIdx.x;
  const int lane = tid & 63, wave = tid >> 6;
  const int r16 = lane & 15, g4 = lane >> 4;
  const int qrow = q0 + wave * 16;

  // K tile: logical [64 rows][16 chunks of 16B]  (row = kv pos, 128 bf16 d-vals)
  // V tile: logical [128 rows][8 chunks of 16B]  (row = d idx,   64 bf16 s-vals)
  __shared__ unsigned short Ks[64 * 128];
  __shared__ unsigned short Vs[128 * 64];
  // wave-private P staging; rows padded to 72 (144B) to break bank conflicts
  __shared__ unsigned short Pl[4][16][72];

  // Q fragments (held across all k-tiles)
  short8 qf[4];
  const unsigned short* Qrow = Qb + ((long)h * S_LEN + qrow + r16) * HD;
#pragma unroll
  for (int kk = 0; kk < 4; ++kk)
    qf[kk] = *(const short8*)(Qrow + kk * 32 + g4 * 8);

  float l_[4] = {0.f, 0.f, 0.f, 0.f};
  f32x4 Of[8] = {};

  const unsigned short* Kbase = Kb + (long)kv * S_LEN * HD;
  const unsigned short* Vbase = VT + (long)kv * HD * S_LEN;

  int jstart = q0 - (WINDOW - 1);
  jstart = (jstart < 0) ? 0 : (jstart & ~63);

  for (int j0 = jstart; j0 < q0 + 64; j0 += 64) {
    __syncthreads();   // previous tile's LDS reads complete before restage
    // ---- stage K tile (1024 chunks) + V tile (1024 chunks); 8 chunks/thread.
    // LDS dest is lane-linear (chunkIdx*16B); global src chunk is inverse-swizzled.
#pragma unroll
    for (int it = 0; it < 4; ++it) {
      int ci = it * 256 + tid;               // K chunk index
      int r  = ci >> 4, c = ci & 15;
      int cl = c ^ (r & 7);
      gload_lds16(Kbase + (long)(j0 + r) * HD + cl * 8, Ks + ci * 8);
    }
#pragma unroll
    for (int it = 0; it < 4; ++it) {
      int ci = it * 256 + tid;               // V chunk index
      int r  = ci >> 3, c = ci & 7;
      int cl = c ^ (r & 7);
      gload_lds16(Vbase + (long)r * S_LEN + j0 + cl * 8, Vs + ci * 8);
    }
    __syncthreads();   // compiler drains vmcnt before barrier

    // ---- S = Q K^T  (64 cols of this tile), K fragments from swizzled LDS
    f32x4 sf[4] = {};
#pragma unroll
    for (int kk = 0; kk < 4; ++kk) {
#pragma unroll
      for (int n = 0; n < 4; ++n) {
        short8 kf = *(const short8*)(Ks + (n * 16 + r16) * 128 +
                                     ((kk * 4 + g4) ^ (r16 & 7)) * 8);
        sf[n] = __builtin_amdgcn_mfma_f32_16x16x32_bf16(qf[kk], kf, sf[n], 0, 0, 0);
      }
    }
    // ---- softcap + band mask + p = exp(capped); accumulate l in-lane (no shfl)
#pragma unroll
    for (int n = 0; n < 4; ++n) {
      int j = j0 + n * 16 + r16;
#pragma unroll
      for (int r = 0; r < 4; ++r) {
        int i = qrow + g4 * 4 + r;
        float v = sf[n][r];
        // 50*tanh(v/50) = 50 - 100/(exp(2v/50)+1); inf-safe at both extremes
        float e = __expf(v * 0.04f);
        float cap = 50.0f - 100.0f * __builtin_amdgcn_rcpf(e + 1.0f);
        bool ok = (j <= i) && (j >= i - (WINDOW - 1));
        float p = ok ? __expf(cap) : 0.0f;   // p in [0, e^50], f32-safe
        l_[r] += p;
        Pl[wave][g4 * 4 + r][n * 16 + r16] = f2bf(p);
      }
    }
    // ---- O += P V   (P from wave-private LDS, V fragments from swizzled LDS)
#pragma unroll
    for (int ks = 0; ks < 2; ++ks) {
      short8 af = *(const short8*)&Pl[wave][r16][ks * 32 + g4 * 8];
#pragma unroll
      for (int n = 0; n < 8; ++n) {
        short8 vf = *(const short8*)(Vs + (n * 16 + r16) * 64 +
                                     ((ks * 4 + g4) ^ (r16 & 7)) * 8);
        Of[n] = __builtin_amdgcn_mfma_f32_16x16x32_bf16(af, vf, Of[n], 0, 0, 0);
      }
    }
  }
  // ---- epilogue: one l-reduction across the 16 k-col lanes, normalize, store
#pragma unroll
  for (int r = 0; r < 4; ++r) {
#pragma unroll
    for (int off = 1; off < 16; off <<= 1)
      l_[r] += __shfl_xor(l_[r], off, 64);
    l_[r] = __builtin_amdgcn_rcpf(l_[r]);
  }
#pragma unroll
  for (int n = 0; n < 8; ++n)
#pragma unroll
    for (int r = 0; r < 4; ++r) {
      int i = qrow + g4 * 4 + r;
      float o = Of[n][r] * l_[r];
      attnB[(long)i * (NH * HD) + h * HD + n * 16 + r16] = f2bf(o);
    }
}

// ---------------------------------------------------------------- launcher
extern "C" void kernel_launch(void* const* d_in, const int* in_sizes, int n_in,
                              void* d_out, int out_size, void* d_ws, size_t ws_size,
                              hipStream_t stream) {
  const float* hidden = (const float*)d_in[0];
  const float* qkv_w  = (const float*)d_in[5];
  const float* o_w    = (const float*)d_in[6];
  float* out = (float*)d_out;
  char* ws = (char*)d_ws;

  // workspace layout (bytes)
  unsigned short* hidB  = (unsigned short*)(ws);                    //  16 MB: [S][HID] bf16
  unsigned short* wqkvT = (unsigned short*)(ws + 16777216L);        //  48 MB: [NQKV][HID] bf16
  unsigned short* woT   = (unsigned short*)(ws + 67108864L);        //  32 MB: [HID][NH*HD] bf16
  float*          qkvF  = (float*)        (ws + 100663296L);        //  48 MB: [S][NQKV] f32
  unsigned short* Qb    = (unsigned short*)(ws + 150994944L);       //  16 MB: [NH][S][HD]
  unsigned short* Kb    = (unsigned short*)(ws + 167772160L);       //   4 MB: [NKV][S][HD]
  unsigned short* VT    = (unsigned short*)(ws + 171966464L);       //   4 MB: [NKV][HD][S]
  unsigned short* attnB = (unsigned short*)(ws + 176160768L);       //  16 MB: [S][NH*HD]
  float*          ropeT = (float*)        (ws + 192937984L);        //   1 MB: [S][64][2]

  // 1) hidden f32 -> bf16
  cast_f32_bf16_kernel<<<(S_LEN * HIDDEN / 4 + 255) / 256, 256, 0, stream>>>(
      hidden, hidB, S_LEN * HIDDEN / 4);
  // 2) qkv_w [HID][NQKV] -> wqkvT [NQKV][HID]
  transpose_cast_kernel<<<dim3(NQKV / 32, HIDDEN / 32, 1), dim3(32, 8), 0, stream>>>(
      qkv_w, wqkvT, NQKV, HIDDEN, 0, 0);
  // 3) o_w [NH*HD][HID] -> woT [HID][NH*HD]
  transpose_cast_kernel<<<dim3(HIDDEN / 32, NH * HD / 32, 1), dim3(32, 8), 0, stream>>>(
      o_w, woT, HIDDEN, NH * HD, 0, 0);
  // 4) rope table
  rope_table_kernel<<<(S_LEN * 64) / 256, 256, 0, stream>>>(ropeT);
  // 5) qkv = hidden @ qkv_w   (f32 out)
  gemm_bt_kernel<<<dim3(NQKV / 128, S_LEN / 128), 256, 0, stream>>>(
      hidB, wqkvT, qkvF, S_LEN, NQKV, HIDDEN);
  // 6) RoPE + scatter Q/K
  rope_scatter_kernel<<<S_LEN, 256, 0, stream>>>(qkvF, ropeT, Qb, Kb);
  // 7) V slice of qkv -> VT [NKV][HD][S]   (per-head transpose)
  transpose_cast_kernel<<<dim3(HD / 32, S_LEN / 32, NKV), dim3(32, 8), 0, stream>>>(
      qkvF + HIDDEN + NKV * HD, VT, NQKV, S_LEN, HD, (long)HD * S_LEN);
  // 8) attention
  attn_kernel<<<dim3(S_LEN / 64, NH), 256, 0, stream>>>(Qb, Kb, VT, attnB);
  // 9) out = attn @ o_w   (f32 out to d_out)
  gemm_bt_kernel<<<dim3(NH * HD / 128, S_LEN / 128), 256, 0, stream>>>(
      attnB, woT, out, S_LEN, NH * HD, HIDDEN);
}

// Round 7
// 563.815 us; speedup vs baseline: 1.4201x; 1.0990x over previous
//
#include <hip/hip_runtime.h>
#include <hip/hip_bf16.h>
#include <cstdint>
#include <cstddef>

// Problem constants
#define S_LEN   2048
#define HIDDEN  4096
#define NH      32
#define NKV     8
#define HD      128
#define NQKV    6144          // (32 + 2*8) * 128
#define WINDOW  1024
#define QSCALE  0.0883883476483184f   // 128^-0.5
#define NEGBIG  -1e30f

typedef __attribute__((ext_vector_type(8))) short  short8;   // 8 bf16 in 4 VGPRs
typedef __attribute__((ext_vector_type(4))) float  f32x4;
typedef __attribute__((ext_vector_type(4))) unsigned short us4;

__device__ __forceinline__ unsigned short f2bf(float f) {
  union { float f; uint32_t u; } v; v.f = f;
  uint32_t r = v.u + 0x7FFFu + ((v.u >> 16) & 1u);   // RNE
  return (unsigned short)(r >> 16);
}

// async global->LDS, 16B per lane. LDS dest must be wave-uniform base + lane*16.
__device__ __forceinline__ void gload_lds16(const void* g, void* l) {
  __builtin_amdgcn_global_load_lds(
      (const __attribute__((address_space(1))) unsigned int*)g,
      (__attribute__((address_space(3))) unsigned int*)l, 16, 0, 0);
}

// ---------------------------------------------------------------- cast f32->bf16
__global__ __launch_bounds__(256) void cast_f32_bf16_kernel(
    const float* __restrict__ src, unsigned short* __restrict__ dst, int n4) {
  int i = blockIdx.x * 256 + threadIdx.x;
  if (i >= n4) return;
  float4 v = ((const float4*)src)[i];
  us4 o; o.x = f2bf(v.x); o.y = f2bf(v.y); o.z = f2bf(v.z); o.w = f2bf(v.w);
  ((us4*)dst)[i] = o;
}

// --------------------------------------------- LDS-tiled transpose + cast f32->bf16
// src logical [R][C] (row stride srstride), dst [C][R] (row stride dstride).
// grid = (C/32, R/32, Z); block = (32, 8)
__global__ __launch_bounds__(256) void transpose_cast_kernel(
    const float* __restrict__ src, unsigned short* __restrict__ dst,
    long srstride, long dstride, long szoff, long dzoff) {
  __shared__ float tile[32][33];
  src += (long)blockIdx.z * szoff;
  dst += (long)blockIdx.z * dzoff;
  const int c0 = blockIdx.x * 32, r0 = blockIdx.y * 32;
  const int tx = threadIdx.x, ty = threadIdx.y;
#pragma unroll
  for (int i = 0; i < 32; i += 8)
    tile[ty + i][tx] = src[(long)(r0 + ty + i) * srstride + c0 + tx];
  __syncthreads();
#pragma unroll
  for (int i = 0; i < 32; i += 8)
    dst[(long)(c0 + ty + i) * dstride + r0 + tx] = f2bf(tile[tx][ty + i]);
}

// ---------------------------------------------------------------- RoPE cos/sin table
// T[s][f][2] for f in [0,64): angle = s * 10000^(-2f/128)
__global__ __launch_bounds__(256) void rope_table_kernel(float* __restrict__ T) {
  int idx = blockIdx.x * 256 + threadIdx.x;   // [0, S*64)
  int pos = idx >> 6, f = idx & 63;
  float inv = powf(10000.0f, -(float)(2 * f) / 128.0f);
  float ang = (float)pos * inv;
  T[idx * 2 + 0] = cosf(ang);
  T[idx * 2 + 1] = sinf(ang);
}

// ------------------------------------------------- RoPE apply + scatter to Q/K layouts
// qkv f32 [S][6144]; Qb [NH][S][HD] (scaled); Kb [NKV][S][HD]
__global__ __launch_bounds__(256) void rope_scatter_kernel(
    const float* __restrict__ qkv, const float* __restrict__ T,
    unsigned short* __restrict__ Qb, unsigned short* __restrict__ Kb) {
  const int s = blockIdx.x;
  const float* row = qkv + (long)s * NQKV;
  const float* tr  = T + (long)s * 128;
#pragma unroll
  for (int it = 0; it < 10; ++it) {
    int hp = it * 256 + threadIdx.x;     // 40 heads * 64 pair-idx = 2560
    int head = hp >> 6, dd = hp & 63;
    float c = tr[dd * 2], sn = tr[dd * 2 + 1];
    int srcoff = (head < NH) ? head * HD : HIDDEN + (head - NH) * HD;
    float x1 = row[srcoff + dd], x2 = row[srcoff + dd + 64];
    float o1 = x1 * c - x2 * sn;
    float o2 = x2 * c + x1 * sn;
    if (head < NH) {
      unsigned short* q = Qb + ((long)head * S_LEN + s) * HD;
      q[dd]      = f2bf(o1 * QSCALE);
      q[dd + 64] = f2bf(o2 * QSCALE);
    } else {
      unsigned short* k = Kb + ((long)(head - NH) * S_LEN + s) * HD;
      k[dd]      = f2bf(o1);
      k[dd + 64] = f2bf(o2);
    }
  }
}

// ---------------------------------------------------------------- GEMM  C = A * B^T
// Deep-pipelined 256-row tile: BM=256, BN=256 or 128 (template), BK=64,
// 512 threads = 8 waves (2 M x 4 N), per-wave output 128 x (BN/4).
// - double-buffered LDS (A 32KB + B 32|16KB per buf); 1 block/CU
// - stage of tile t+1 issued BEFORE tile t's compute; the only vmcnt drain is
//   the iteration-boundary __syncthreads() -> issue-to-wait distance = full
//   K-tile of MFMAs (HBM latency hidden)
// - T2 XOR swizzle (chunk ^= row&7, 16B chunks) applied on the GLOBAL source
//   during staging (LDS dest lane-linear, as global_load_lds requires) and on
//   the ds_read side -> conflict-free b128 reads (else 16-way: lanes 0-15
//   stride 128B hit one bank group)
// - kk0/kk1 phase split with raw s_barrier + setprio(1) around each 32-MFMA
//   cluster (role-split regime where T2/T5 pay)
template<int BN>
__global__ __launch_bounds__(512, 2) void gemm8p_kernel(
    const unsigned short* __restrict__ A, const unsigned short* __restrict__ BT,
    float* __restrict__ C, int M, int N, int K) {
  constexpr int WN  = BN / 4;        // per-wave N extent
  constexpr int NFR = WN / 16;       // B fragments per kk (4 or 2)
  constexpr int ASZ = 256 * 64;      // shorts per A buffer
  constexpr int BSZ = BN * 64;       // shorts per B buffer

  __shared__ unsigned short lds[2 * (ASZ + BSZ)];

  const int tid  = threadIdx.x;
  const int lane = tid & 63, wave = tid >> 6;
  const int wm = wave >> 2, wn = wave & 3;
  const int r16 = lane & 15, g4 = lane >> 4;

  // XCD-aware swizzle (both grids are multiples of 8 workgroups)
  const int nwg  = gridDim.x * gridDim.y;
  const int orig = blockIdx.y * gridDim.x + blockIdx.x;
  const int swz  = (orig & 7) * (nwg >> 3) + (orig >> 3);
  const long bm = (long)(swz / gridDim.x) * 256;
  const long bn = (long)(swz % gridDim.x) * BN;

  f32x4 acc[8][NFR] = {};

  auto STAGE = [&](int k0, int buf) {
    unsigned short* la = lds + buf * (ASZ + BSZ);
    unsigned short* lb = la + ASZ;
#pragma unroll
    for (int j = 0; j < 4; ++j) {                 // A: 2048 chunks of 16B
      int ci = tid + j * 512;
      int row = ci >> 3, cl = (ci & 7) ^ (row & 7);
      gload_lds16(A + (bm + row) * K + k0 + cl * 8, la + ci * 8);
    }
#pragma unroll
    for (int j = 0; j < BN / 64; ++j) {           // B: BN*8 chunks
      int ci = tid + j * 512;
      int row = ci >> 3, cl = (ci & 7) ^ (row & 7);
      gload_lds16(BT + (bn + row) * K + k0 + cl * 8, lb + ci * 8);
    }
  };

  const int NT = K >> 6;
  STAGE(0, 0);
  __syncthreads();                                 // drains vmcnt: buf0 ready

  for (int t = 0; t < NT; ++t) {
    const int cur = t & 1;
    const unsigned short* la = lds + cur * (ASZ + BSZ);
    const unsigned short* lb = la + ASZ;
    if (t + 1 < NT) STAGE((t + 1) << 6, cur ^ 1);  // issue-early prefetch
#pragma unroll
    for (int kk = 0; kk < 2; ++kk) {
      short8 af[8], bf[NFR];
#pragma unroll
      for (int m = 0; m < 8; ++m) {
        int row = wm * 128 + m * 16 + r16;
        af[m] = *(const short8*)(la + row * 64 + (((kk << 2) | g4) ^ (r16 & 7)) * 8);
      }
#pragma unroll
      for (int n = 0; n < NFR; ++n) {
        int row = wn * WN + n * 16 + r16;
        bf[n] = *(const short8*)(lb + row * 64 + (((kk << 2) | g4) ^ (r16 & 7)) * 8);
      }
      __builtin_amdgcn_s_barrier();                // phase split (no vm drain)
      __builtin_amdgcn_s_setprio(1);
#pragma unroll
      for (int m = 0; m < 8; ++m)
#pragma unroll
        for (int n = 0; n < NFR; ++n)
          acc[m][n] = __builtin_amdgcn_mfma_f32_16x16x32_bf16(af[m], bf[n], acc[m][n], 0, 0, 0);
      __builtin_amdgcn_s_setprio(0);
      if (kk == 0) __builtin_amdgcn_s_barrier();
    }
    __syncthreads();   // boundary: drains vmcnt(0) (tile t+1 staged) + lgkm
  }

  float* Cp = C + (bm + wm * 128) * N + bn + wn * WN;
#pragma unroll
  for (int m = 0; m < 8; ++m)
#pragma unroll
    for (int n = 0; n < NFR; ++n)
#pragma unroll
      for (int r = 0; r < 4; ++r)
        Cp[(long)(m * 16 + g4 * 4 + r) * N + n * 16 + r16] = acc[m][n][r];
}

// ---------------------------------------------------------------- banded flash attention
// Qb [NH][S][HD] (pre-scaled), Kb [NKV][S][HD], VT [NKV][HD][S], out attnB [S][NH*HD]
// block = (64-row q-tile, head); 4 waves x 16 rows. K-tile = 64.
// K/V staged in LDS once per block (XOR-swizzled via pre-swizzled global src);
// softcap bounds scores to (-50,50) so no running max / rescale is needed.
__global__ __launch_bounds__(256) void attn_kernel(
    const unsigned short* __restrict__ Qb, const unsigned short* __restrict__ Kb,
    const unsigned short* __restrict__ VT, unsigned short* __restrict__ attnB) {
  const int h  = blockIdx.y;
  // diagonal remap: CU c would otherwise get 4 blocks of identical q-tile index
  // (grid.x=32 divides 256) -> 17x work imbalance across CUs. Spread it.
  const int qt = (blockIdx.x + blockIdx.y) & 31;
  const int q0 = qt * 64;
  const int kv = h >> 2;                      // H/KV = 4
  const int tid  = threadIdx.x;
  const int lane = tid & 63, wave = tid >> 6;
  const int r16 = lane & 15, g4 = lane >> 4;
  const int qrow = q0 + wave * 16;

  // K tile: logical [64 rows][16 chunks of 16B]  (row = kv pos, 128 bf16 d-vals)
  // V tile: logical [128 rows][8 chunks of 16B]  (row = d idx,   64 bf16 s-vals)
  __shared__ unsigned short Ks[64 * 128];
  __shared__ unsigned short Vs[128 * 64];
  // wave-private P staging; rows padded to 72 (144B) to break bank conflicts
  __shared__ unsigned short Pl[4][16][72];

  // Q fragments (held across all k-tiles)
  short8 qf[4];
  const unsigned short* Qrow = Qb + ((long)h * S_LEN + qrow + r16) * HD;
#pragma unroll
  for (int kk = 0; kk < 4; ++kk)
    qf[kk] = *(const short8*)(Qrow + kk * 32 + g4 * 8);

  float l_[4] = {0.f, 0.f, 0.f, 0.f};
  f32x4 Of[8] = {};

  const unsigned short* Kbase = Kb + (long)kv * S_LEN * HD;
  const unsigned short* Vbase = VT + (long)kv * HD * S_LEN;

  int jstart = q0 - (WINDOW - 1);
  jstart = (jstart < 0) ? 0 : (jstart & ~63);

  for (int j0 = jstart; j0 < q0 + 64; j0 += 64) {
    __syncthreads();   // previous tile's LDS reads complete before restage
    // ---- stage K tile (1024 chunks) + V tile (1024 chunks); 8 chunks/thread.
    // LDS dest is lane-linear (chunkIdx*16B); global src chunk is inverse-swizzled.
#pragma unroll
    for (int it = 0; it < 4; ++it) {
      int ci = it * 256 + tid;               // K chunk index
      int r  = ci >> 4, c = ci & 15;
      int cl = c ^ (r & 7);
      gload_lds16(Kbase + (long)(j0 + r) * HD + cl * 8, Ks + ci * 8);
    }
#pragma unroll
    for (int it = 0; it < 4; ++it) {
      int ci = it * 256 + tid;               // V chunk index
      int r  = ci >> 3, c = ci & 7;
      int cl = c ^ (r & 7);
      gload_lds16(Vbase + (long)r * S_LEN + j0 + cl * 8, Vs + ci * 8);
    }
    __syncthreads();   // compiler drains vmcnt before barrier

    // ---- S = Q K^T  (64 cols of this tile), K fragments from swizzled LDS
    f32x4 sf[4] = {};
#pragma unroll
    for (int kk = 0; kk < 4; ++kk) {
#pragma unroll
      for (int n = 0; n < 4; ++n) {
        short8 kf = *(const short8*)(Ks + (n * 16 + r16) * 128 +
                                     ((kk * 4 + g4) ^ (r16 & 7)) * 8);
        sf[n] = __builtin_amdgcn_mfma_f32_16x16x32_bf16(qf[kk], kf, sf[n], 0, 0, 0);
      }
    }
    // ---- softcap + band mask + p = exp(capped); accumulate l in-lane (no shfl)
#pragma unroll
    for (int n = 0; n < 4; ++n) {
      int j = j0 + n * 16 + r16;
#pragma unroll
      for (int r = 0; r < 4; ++r) {
        int i = qrow + g4 * 4 + r;
        float v = sf[n][r];
        // 50*tanh(v/50) = 50 - 100/(exp(2v/50)+1); inf-safe at both extremes
        float e = __expf(v * 0.04f);
        float cap = 50.0f - 100.0f * __builtin_amdgcn_rcpf(e + 1.0f);
        bool ok = (j <= i) && (j >= i - (WINDOW - 1));
        float p = ok ? __expf(cap) : 0.0f;   // p in [0, e^50], f32-safe
        l_[r] += p;
        Pl[wave][g4 * 4 + r][n * 16 + r16] = f2bf(p);
      }
    }
    // ---- O += P V   (P from wave-private LDS, V fragments from swizzled LDS)
#pragma unroll
    for (int ks = 0; ks < 2; ++ks) {
      short8 af = *(const short8*)&Pl[wave][r16][ks * 32 + g4 * 8];
#pragma unroll
      for (int n = 0; n < 8; ++n) {
        short8 vf = *(const short8*)(Vs + (n * 16 + r16) * 64 +
                                     ((ks * 4 + g4) ^ (r16 & 7)) * 8);
        Of[n] = __builtin_amdgcn_mfma_f32_16x16x32_bf16(af, vf, Of[n], 0, 0, 0);
      }
    }
  }
  // ---- epilogue: one l-reduction across the 16 k-col lanes, normalize, store
#pragma unroll
  for (int r = 0; r < 4; ++r) {
#pragma unroll
    for (int off = 1; off < 16; off <<= 1)
      l_[r] += __shfl_xor(l_[r], off, 64);
    l_[r] = __builtin_amdgcn_rcpf(l_[r]);
  }
#pragma unroll
  for (int n = 0; n < 8; ++n)
#pragma unroll
    for (int r = 0; r < 4; ++r) {
      int i = qrow + g4 * 4 + r;
      float o = Of[n][r] * l_[r];
      attnB[(long)i * (NH * HD) + h * HD + n * 16 + r16] = f2bf(o);
    }
}

// ---------------------------------------------------------------- launcher
extern "C" void kernel_launch(void* const* d_in, const int* in_sizes, int n_in,
                              void* d_out, int out_size, void* d_ws, size_t ws_size,
                              hipStream_t stream) {
  const float* hidden = (const float*)d_in[0];
  const float* qkv_w  = (const float*)d_in[5];
  const float* o_w    = (const float*)d_in[6];
  float* out = (float*)d_out;
  char* ws = (char*)d_ws;

  // workspace layout (bytes)
  unsigned short* hidB  = (unsigned short*)(ws);                    //  16 MB: [S][HID] bf16
  unsigned short* wqkvT = (unsigned short*)(ws + 16777216L);        //  48 MB: [NQKV][HID] bf16
  unsigned short* woT   = (unsigned short*)(ws + 67108864L);        //  32 MB: [HID][NH*HD] bf16
  float*          qkvF  = (float*)        (ws + 100663296L);        //  48 MB: [S][NQKV] f32
  unsigned short* Qb    = (unsigned short*)(ws + 150994944L);       //  16 MB: [NH][S][HD]
  unsigned short* Kb    = (unsigned short*)(ws + 167772160L);       //   4 MB: [NKV][S][HD]
  unsigned short* VT    = (unsigned short*)(ws + 171966464L);       //   4 MB: [NKV][HD][S]
  unsigned short* attnB = (unsigned short*)(ws + 176160768L);       //  16 MB: [S][NH*HD]
  float*          ropeT = (float*)        (ws + 192937984L);        //   1 MB: [S][64][2]

  // 1) hidden f32 -> bf16
  cast_f32_bf16_kernel<<<(S_LEN * HIDDEN / 4 + 255) / 256, 256, 0, stream>>>(
      hidden, hidB, S_LEN * HIDDEN / 4);
  // 2) qkv_w [HID][NQKV] -> wqkvT [NQKV][HID]
  transpose_cast_kernel<<<dim3(NQKV / 32, HIDDEN / 32, 1), dim3(32, 8), 0, stream>>>(
      qkv_w, wqkvT, NQKV, HIDDEN, 0, 0);
  // 3) o_w [NH*HD][HID] -> woT [HID][NH*HD]
  transpose_cast_kernel<<<dim3(HIDDEN / 32, NH * HD / 32, 1), dim3(32, 8), 0, stream>>>(
      o_w, woT, HIDDEN, NH * HD, 0, 0);
  // 4) rope table
  rope_table_kernel<<<(S_LEN * 64) / 256, 256, 0, stream>>>(ropeT);
  // 5) qkv = hidden @ qkv_w   (f32 out); tiles 256x256, grid 24x8 = 192 wgs
  gemm8p_kernel<256><<<dim3(NQKV / 256, S_LEN / 256), 512, 0, stream>>>(
      hidB, wqkvT, qkvF, S_LEN, NQKV, HIDDEN);
  // 6) RoPE + scatter Q/K
  rope_scatter_kernel<<<S_LEN, 256, 0, stream>>>(qkvF, ropeT, Qb, Kb);
  // 7) V slice of qkv -> VT [NKV][HD][S]   (per-head transpose)
  transpose_cast_kernel<<<dim3(HD / 32, S_LEN / 32, NKV), dim3(32, 8), 0, stream>>>(
      qkvF + HIDDEN + NKV * HD, VT, NQKV, S_LEN, HD, (long)HD * S_LEN);
  // 8) attention
  attn_kernel<<<dim3(S_LEN / 64, NH), 256, 0, stream>>>(Qb, Kb, VT, attnB);
  // 9) out = attn @ o_w; tiles 256x128, grid 32x8 = 256 wgs (full CU coverage)
  gemm8p_kernel<128><<<dim3(NH * HD / 128, S_LEN / 256), 512, 0, stream>>>(
      attnB, woT, out, S_LEN, NH * HD, HIDDEN);
}

// Round 9
// 538.429 us; speedup vs baseline: 1.4870x; 1.0471x over previous
//
#include <hip/hip_runtime.h>
#include <hip/hip_bf16.h>
#include <cstdint>
#include <cstddef>

// Problem constants
#define S_LEN   2048
#define HIDDEN  4096
#define NH      32
#define NKV     8
#define HD      128
#define NQKV    6144          // (32 + 2*8) * 128
#define WINDOW  1024
#define QSCALE  0.0883883476483184f   // 128^-0.5
#define NEGBIG  -1e30f

typedef __attribute__((ext_vector_type(8))) short  short8;   // 8 bf16 in 4 VGPRs
typedef __attribute__((ext_vector_type(4))) float  f32x4;
typedef __attribute__((ext_vector_type(4))) unsigned short us4;

__device__ __forceinline__ unsigned short f2bf(float f) {
  union { float f; uint32_t u; } v; v.f = f;
  uint32_t r = v.u + 0x7FFFu + ((v.u >> 16) & 1u);   // RNE
  return (unsigned short)(r >> 16);
}

// async global->LDS, 16B per lane. LDS dest must be wave-uniform base + lane*16.
__device__ __forceinline__ void gload_lds16(const void* g, void* l) {
  __builtin_amdgcn_global_load_lds(
      (const __attribute__((address_space(1))) unsigned int*)g,
      (__attribute__((address_space(3))) unsigned int*)l, 16, 0, 0);
}

// ---------------------------------------------------------------- cast f32->bf16
__global__ __launch_bounds__(256) void cast_f32_bf16_kernel(
    const float* __restrict__ src, unsigned short* __restrict__ dst, int n4) {
  int i = blockIdx.x * 256 + threadIdx.x;
  if (i >= n4) return;
  float4 v = ((const float4*)src)[i];
  us4 o; o.x = f2bf(v.x); o.y = f2bf(v.y); o.z = f2bf(v.z); o.w = f2bf(v.w);
  ((us4*)dst)[i] = o;
}

// --------------------------------------------- LDS-tiled transpose + cast f32->bf16
// src logical [R][C] (row stride srstride), dst [C][R] (row stride dstride).
// grid = (C/32, R/32, Z); block = (32, 8)
__global__ __launch_bounds__(256) void transpose_cast_kernel(
    const float* __restrict__ src, unsigned short* __restrict__ dst,
    long srstride, long dstride, long szoff, long dzoff) {
  __shared__ float tile[32][33];
  src += (long)blockIdx.z * szoff;
  dst += (long)blockIdx.z * dzoff;
  const int c0 = blockIdx.x * 32, r0 = blockIdx.y * 32;
  const int tx = threadIdx.x, ty = threadIdx.y;
#pragma unroll
  for (int i = 0; i < 32; i += 8)
    tile[ty + i][tx] = src[(long)(r0 + ty + i) * srstride + c0 + tx];
  __syncthreads();
#pragma unroll
  for (int i = 0; i < 32; i += 8)
    dst[(long)(c0 + ty + i) * dstride + r0 + tx] = f2bf(tile[tx][ty + i]);
}

// ---------------------------------------------------------------- RoPE cos/sin table
// T[s][f][2] for f in [0,64): angle = s * 10000^(-2f/128)
__global__ __launch_bounds__(256) void rope_table_kernel(float* __restrict__ T) {
  int idx = blockIdx.x * 256 + threadIdx.x;   // [0, S*64)
  int pos = idx >> 6, f = idx & 63;
  float inv = powf(10000.0f, -(float)(2 * f) / 128.0f);
  float ang = (float)pos * inv;
  T[idx * 2 + 0] = cosf(ang);
  T[idx * 2 + 1] = sinf(ang);
}

// ------------------------------------------------- RoPE apply + scatter to Q/K layouts
// qkv f32 [S][6144]; Qb [NH][S][HD] (scaled); Kb [NKV][S][HD]
__global__ __launch_bounds__(256) void rope_scatter_kernel(
    const float* __restrict__ qkv, const float* __restrict__ T,
    unsigned short* __restrict__ Qb, unsigned short* __restrict__ Kb) {
  const int s = blockIdx.x;
  const float* row = qkv + (long)s * NQKV;
  const float* tr  = T + (long)s * 128;
#pragma unroll
  for (int it = 0; it < 10; ++it) {
    int hp = it * 256 + threadIdx.x;     // 40 heads * 64 pair-idx = 2560
    int head = hp >> 6, dd = hp & 63;
    float c = tr[dd * 2], sn = tr[dd * 2 + 1];
    int srcoff = (head < NH) ? head * HD : HIDDEN + (head - NH) * HD;
    float x1 = row[srcoff + dd], x2 = row[srcoff + dd + 64];
    float o1 = x1 * c - x2 * sn;
    float o2 = x2 * c + x1 * sn;
    if (head < NH) {
      unsigned short* q = Qb + ((long)head * S_LEN + s) * HD;
      q[dd]      = f2bf(o1 * QSCALE);
      q[dd + 64] = f2bf(o2 * QSCALE);
    } else {
      unsigned short* k = Kb + ((long)(head - NH) * S_LEN + s) * HD;
      k[dd]      = f2bf(o1);
      k[dd + 64] = f2bf(o2);
    }
  }
}

// ---------------------------------------------------------------- GEMM  C = A * B^T
// Pipelined tile: BM=256, BN=192|128 (template), BK=64, 512 threads = 8 waves
// (2M x 4N), per-wave output 128 x (BN/4). Double-buffered LDS.
// R7 schedule (counted-vmcnt 2-barrier loop; catalog T3/T4 recipe):
//   per tile: STAGE(t+1 -> buf^1); s_waitcnt vmcnt(L)   [L = loads just issued,
//             so the PREVIOUS tile's loads are drained, new ones stay in flight];
//             s_barrier  [all waves' staging of buf[cur] visible];
//             free-running kk0/kk1 compute (no mid barriers -> waves stagger,
//             MFMA of one wave covers ds_read of another; setprio(1) on MFMA);
//             s_barrier  [reads of buf[cur] done before next STAGE overwrites].
//   vmcnt never drains to 0 in the main loop (m218: that drain was the 2-phase
//   ceiling). T2 XOR swizzle on LDS via pre-swizzled global source (R5-proven).
// Grid sized to exactly 256 workgroups for both calls (full CU coverage).
template<int BN>
__global__ __launch_bounds__(512, 2) void gemm8p_kernel(
    const unsigned short* __restrict__ A, const unsigned short* __restrict__ BT,
    float* __restrict__ C, int M, int N, int K) {
  constexpr int WN  = BN / 4;        // per-wave N extent
  constexpr int NFR = WN / 16;       // B fragments per kk
  constexpr int ASZ = 256 * 64;      // shorts per A buffer
  constexpr int BSZ = BN * 64;       // shorts per B buffer

  __shared__ unsigned short lds[2 * (ASZ + BSZ)];

  const int tid  = threadIdx.x;
  const int lane = tid & 63, wave = tid >> 6;
  const int wm = wave >> 2, wn = wave & 3;
  const int r16 = lane & 15, g4 = lane >> 4;

  // XCD-aware swizzle (both grids are exactly 256 workgroups, 256 % 8 == 0)
  const int nwg  = gridDim.x * gridDim.y;
  const int orig = blockIdx.y * gridDim.x + blockIdx.x;
  const int swz  = (orig & 7) * (nwg >> 3) + (orig >> 3);
  const long bm = (long)(swz / gridDim.x) * 256;
  const long bn = (long)(swz % gridDim.x) * BN;

  f32x4 acc[8][NFR] = {};

  auto STAGE = [&](int k0, int buf) {
    unsigned short* la = lds + buf * (ASZ + BSZ);
    unsigned short* lb = la + ASZ;
#pragma unroll
    for (int j = 0; j < 4; ++j) {                 // A: 2048 chunks of 16B
      int ci = tid + j * 512;
      int row = ci >> 3, cl = (ci & 7) ^ (row & 7);
      gload_lds16(A + (bm + row) * K + k0 + cl * 8, la + ci * 8);
    }
#pragma unroll
    for (int j = 0; j < BN / 64; ++j) {           // B: BN*8 chunks
      int ci = tid + j * 512;
      int row = ci >> 3, cl = (ci & 7) ^ (row & 7);
      gload_lds16(BT + (bn + row) * K + k0 + cl * 8, lb + ci * 8);
    }
  };

  const int NT = K >> 6;
  STAGE(0, 0);                                    // prologue prefetch

  for (int t = 0; t < NT; ++t) {
    const int cur = t & 1;
    const unsigned short* la = lds + cur * (ASZ + BSZ);
    const unsigned short* lb = la + ASZ;
    if (t + 1 < NT) {
      STAGE((t + 1) << 6, cur ^ 1);               // issue next tile's loads
      // wait for PREVIOUS tile's loads only (own-wave FIFO); new L stay in flight
      if constexpr (BN == 192) asm volatile("s_waitcnt vmcnt(7)" ::: "memory");
      else                     asm volatile("s_waitcnt vmcnt(6)" ::: "memory");
    } else {
      asm volatile("s_waitcnt vmcnt(0)" ::: "memory");
    }
    __builtin_amdgcn_s_barrier();                 // buf[cur] valid block-wide

#pragma unroll
    for (int kk = 0; kk < 2; ++kk) {
      short8 af[8], bf[NFR];
#pragma unroll
      for (int m = 0; m < 8; ++m) {
        int row = wm * 128 + m * 16 + r16;
        af[m] = *(const short8*)(la + row * 64 + (((kk << 2) | g4) ^ (r16 & 7)) * 8);
      }
#pragma unroll
      for (int n = 0; n < NFR; ++n) {
        int row = wn * WN + n * 16 + r16;
        bf[n] = *(const short8*)(lb + row * 64 + (((kk << 2) | g4) ^ (r16 & 7)) * 8);
      }
      __builtin_amdgcn_s_setprio(1);
#pragma unroll
      for (int m = 0; m < 8; ++m)
#pragma unroll
        for (int n = 0; n < NFR; ++n)
          acc[m][n] = __builtin_amdgcn_mfma_f32_16x16x32_bf16(af[m], bf[n], acc[m][n], 0, 0, 0);
      __builtin_amdgcn_s_setprio(0);
    }
    __builtin_amdgcn_s_barrier();   // reads of buf[cur] done before t+1 STAGE
  }

  float* Cp = C + (bm + wm * 128) * N + bn + wn * WN;
#pragma unroll
  for (int m = 0; m < 8; ++m)
#pragma unroll
    for (int n = 0; n < NFR; ++n)
#pragma unroll
      for (int r = 0; r < 4; ++r)
        Cp[(long)(m * 16 + g4 * 4 + r) * N + n * 16 + r16] = acc[m][n][r];
}

// ---------------------------------------------------------------- banded flash attention
// Qb [NH][S][HD] (pre-scaled), Kb [NKV][S][HD], VT [NKV][HD][S], out attnB [S][NH*HD]
// block = (64-row q-tile, head); 4 waves x 16 rows. K-tile = 64.
// K/V staged in LDS once per block (XOR-swizzled via pre-swizzled global src);
// softcap bounds scores to (-50,50) so no running max / rescale is needed.
__global__ __launch_bounds__(256) void attn_kernel(
    const unsigned short* __restrict__ Qb, const unsigned short* __restrict__ Kb,
    const unsigned short* __restrict__ VT, unsigned short* __restrict__ attnB) {
  const int h  = blockIdx.y;
  // diagonal remap: CU c would otherwise get 4 blocks of identical q-tile index
  // (grid.x=32 divides 256) -> 17x work imbalance across CUs. Spread it.
  const int qt = (blockIdx.x + blockIdx.y) & 31;
  const int q0 = qt * 64;
  const int kv = h >> 2;                      // H/KV = 4
  const int tid  = threadIdx.x;
  const int lane = tid & 63, wave = tid >> 6;
  const int r16 = lane & 15, g4 = lane >> 4;
  const int qrow = q0 + wave * 16;

  // K tile: logical [64 rows][16 chunks of 16B]  (row = kv pos, 128 bf16 d-vals)
  // V tile: logical [128 rows][8 chunks of 16B]  (row = d idx,   64 bf16 s-vals)
  __shared__ unsigned short Ks[64 * 128];
  __shared__ unsigned short Vs[128 * 64];
  // wave-private P staging; rows padded to 72 (144B) to break bank conflicts
  __shared__ unsigned short Pl[4][16][72];

  // Q fragments (held across all k-tiles)
  short8 qf[4];
  const unsigned short* Qrow = Qb + ((long)h * S_LEN + qrow + r16) * HD;
#pragma unroll
  for (int kk = 0; kk < 4; ++kk)
    qf[kk] = *(const short8*)(Qrow + kk * 32 + g4 * 8);

  float l_[4] = {0.f, 0.f, 0.f, 0.f};
  f32x4 Of[8] = {};

  const unsigned short* Kbase = Kb + (long)kv * S_LEN * HD;
  const unsigned short* Vbase = VT + (long)kv * HD * S_LEN;

  int jstart = q0 - (WINDOW - 1);
  jstart = (jstart < 0) ? 0 : (jstart & ~63);

  for (int j0 = jstart; j0 < q0 + 64; j0 += 64) {
    __syncthreads();   // previous tile's LDS reads complete before restage
    // ---- stage K tile (1024 chunks) + V tile (1024 chunks); 8 chunks/thread.
    // LDS dest is lane-linear (chunkIdx*16B); global src chunk is inverse-swizzled.
#pragma unroll
    for (int it = 0; it < 4; ++it) {
      int ci = it * 256 + tid;               // K chunk index
      int r  = ci >> 4, c = ci & 15;
      int cl = c ^ (r & 7);
      gload_lds16(Kbase + (long)(j0 + r) * HD + cl * 8, Ks + ci * 8);
    }
#pragma unroll
    for (int it = 0; it < 4; ++it) {
      int ci = it * 256 + tid;               // V chunk index
      int r  = ci >> 3, c = ci & 7;
      int cl = c ^ (r & 7);
      gload_lds16(Vbase + (long)r * S_LEN + j0 + cl * 8, Vs + ci * 8);
    }
    __syncthreads();   // compiler drains vmcnt before barrier

    // ---- S = Q K^T  (64 cols of this tile), K fragments from swizzled LDS
    f32x4 sf[4] = {};
#pragma unroll
    for (int kk = 0; kk < 4; ++kk) {
#pragma unroll
      for (int n = 0; n < 4; ++n) {
        short8 kf = *(const short8*)(Ks + (n * 16 + r16) * 128 +
                                     ((kk * 4 + g4) ^ (r16 & 7)) * 8);
        sf[n] = __builtin_amdgcn_mfma_f32_16x16x32_bf16(qf[kk], kf, sf[n], 0, 0, 0);
      }
    }
    // ---- softcap + band mask + p = exp(capped); accumulate l in-lane (no shfl)
#pragma unroll
    for (int n = 0; n < 4; ++n) {
      int j = j0 + n * 16 + r16;
#pragma unroll
      for (int r = 0; r < 4; ++r) {
        int i = qrow + g4 * 4 + r;
        float v = sf[n][r];
        // 50*tanh(v/50) = 50 - 100/(exp(2v/50)+1); inf-safe at both extremes
        float e = __expf(v * 0.04f);
        float cap = 50.0f - 100.0f * __builtin_amdgcn_rcpf(e + 1.0f);
        bool ok = (j <= i) && (j >= i - (WINDOW - 1));
        float p = ok ? __expf(cap) : 0.0f;   // p in [0, e^50], f32-safe
        l_[r] += p;
        Pl[wave][g4 * 4 + r][n * 16 + r16] = f2bf(p);
      }
    }
    // ---- O += P V   (P from wave-private LDS, V fragments from swizzled LDS)
#pragma unroll
    for (int ks = 0; ks < 2; ++ks) {
      short8 af = *(const short8*)&Pl[wave][r16][ks * 32 + g4 * 8];
#pragma unroll
      for (int n = 0; n < 8; ++n) {
        short8 vf = *(const short8*)(Vs + (n * 16 + r16) * 64 +
                                     ((ks * 4 + g4) ^ (r16 & 7)) * 8);
        Of[n] = __builtin_amdgcn_mfma_f32_16x16x32_bf16(af, vf, Of[n], 0, 0, 0);
      }
    }
  }
  // ---- epilogue: one l-reduction across the 16 k-col lanes, normalize, store
#pragma unroll
  for (int r = 0; r < 4; ++r) {
#pragma unroll
    for (int off = 1; off < 16; off <<= 1)
      l_[r] += __shfl_xor(l_[r], off, 64);
    l_[r] = __builtin_amdgcn_rcpf(l_[r]);
  }
#pragma unroll
  for (int n = 0; n < 8; ++n)
#pragma unroll
    for (int r = 0; r < 4; ++r) {
      int i = qrow + g4 * 4 + r;
      float o = Of[n][r] * l_[r];
      attnB[(long)i * (NH * HD) + h * HD + n * 16 + r16] = f2bf(o);
    }
}

// ---------------------------------------------------------------- launcher
extern "C" void kernel_launch(void* const* d_in, const int* in_sizes, int n_in,
                              void* d_out, int out_size, void* d_ws, size_t ws_size,
                              hipStream_t stream) {
  const float* hidden = (const float*)d_in[0];
  const float* qkv_w  = (const float*)d_in[5];
  const float* o_w    = (const float*)d_in[6];
  float* out = (float*)d_out;
  char* ws = (char*)d_ws;

  // workspace layout (bytes)
  unsigned short* hidB  = (unsigned short*)(ws);                    //  16 MB: [S][HID] bf16
  unsigned short* wqkvT = (unsigned short*)(ws + 16777216L);        //  48 MB: [NQKV][HID] bf16
  unsigned short* woT   = (unsigned short*)(ws + 67108864L);        //  32 MB: [HID][NH*HD] bf16
  float*          qkvF  = (float*)        (ws + 100663296L);        //  48 MB: [S][NQKV] f32
  unsigned short* Qb    = (unsigned short*)(ws + 150994944L);       //  16 MB: [NH][S][HD]
  unsigned short* Kb    = (unsigned short*)(ws + 167772160L);       //   4 MB: [NKV][S][HD]
  unsigned short* VT    = (unsigned short*)(ws + 171966464L);       //   4 MB: [NKV][HD][S]
  unsigned short* attnB = (unsigned short*)(ws + 176160768L);       //  16 MB: [S][NH*HD]
  float*          ropeT = (float*)        (ws + 192937984L);        //   1 MB: [S][64][2]

  // 1) hidden f32 -> bf16
  cast_f32_bf16_kernel<<<(S_LEN * HIDDEN / 4 + 255) / 256, 256, 0, stream>>>(
      hidden, hidB, S_LEN * HIDDEN / 4);
  // 2) qkv_w [HID][NQKV] -> wqkvT [NQKV][HID]
  transpose_cast_kernel<<<dim3(NQKV / 32, HIDDEN / 32, 1), dim3(32, 8), 0, stream>>>(
      qkv_w, wqkvT, NQKV, HIDDEN, 0, 0);
  // 3) o_w [NH*HD][HID] -> woT [HID][NH*HD]
  transpose_cast_kernel<<<dim3(HIDDEN / 32, NH * HD / 32, 1), dim3(32, 8), 0, stream>>>(
      o_w, woT, HIDDEN, NH * HD, 0, 0);
  // 4) rope table
  rope_table_kernel<<<(S_LEN * 64) / 256, 256, 0, stream>>>(ropeT);
  // 5) qkv = hidden @ qkv_w; tiles 256x192, grid 32x8 = 256 wgs (full coverage)
  gemm8p_kernel<192><<<dim3(NQKV / 192, S_LEN / 256), 512, 0, stream>>>(
      hidB, wqkvT, qkvF, S_LEN, NQKV, HIDDEN);
  // 6) RoPE + scatter Q/K
  rope_scatter_kernel<<<S_LEN, 256, 0, stream>>>(qkvF, ropeT, Qb, Kb);
  // 7) V slice of qkv -> VT [NKV][HD][S]   (per-head transpose)
  transpose_cast_kernel<<<dim3(HD / 32, S_LEN / 32, NKV), dim3(32, 8), 0, stream>>>(
      qkvF + HIDDEN + NKV * HD, VT, NQKV, S_LEN, HD, (long)HD * S_LEN);
  // 8) attention
  attn_kernel<<<dim3(S_LEN / 64, NH), 256, 0, stream>>>(Qb, Kb, VT, attnB);
  // 9) out = attn @ o_w; tiles 256x128, grid 32x8 = 256 wgs (full CU coverage)
  gemm8p_kernel<128><<<dim3(NH * HD / 128, S_LEN / 256), 512, 0, stream>>>(
      attnB, woT, out, S_LEN, NH * HD, HIDDEN);
}